// Round 9
// baseline (181.421 us; speedup 1.0000x reference)
//
#include <hip/hip_runtime.h>
#include <math.h>

#define B_  16
#define L_  4096
#define D_  64
#define R_  4
#define NB_ 64
#define BL_ 64
#define FIXCAP 8192

typedef _Float16 f16x8 __attribute__((ext_vector_type(8)));
typedef _Float16 f16x2 __attribute__((ext_vector_type(2)));
typedef float    f32x4 __attribute__((ext_vector_type(4)));

// ---------------- ws layout ----------------
// [0MB,1MB)     rmn    double   [B][R][32][64]
// [1MB,2MB)     h      int      [B][R][L]
// [2MB,3MB)     hi     int      [B][R][L]
// [3MB,4MB)     oi     int      [B][R][L]
// [4MB,5MB)     lse    float    [B][R][L]   (original index)
// [5MB,+256)    rwmax float[64]; [+256,+512) rwsum; [+512] fix_cnt; [+1024,) fix_list
// [6MB,40MB)    attn   _Float16 [B][L][R][64]  (original index, round-minor)
// [40MB,+256K)  rhi    _Float16 [B][128][64]
// [40.5MB,+256K)rlo    _Float16 [B][128][64]
// [41MB,45MB)   meta   int4     [B*R][L]
// [45MB,53MB)   qhf    _Float16 [B][L][64]   raw q, f16
// [53MB,61MB)   khf    _Float16 [B][L][64]   q/||q||/8, f16
// [61MB,69MB)   vhf    _Float16 [B][L][64]   v, f16

// K0: normalize rand_matrix along d, store fp64 + split-f16 copies; zero fix_cnt.
__global__ __launch_bounds__(64) void k_rmnorm(const float* __restrict__ rm,
                                               double* __restrict__ rmn,
                                               _Float16* __restrict__ rhi_g,
                                               _Float16* __restrict__ rlo_g,
                                               int* __restrict__ fix_cnt) {
    if (blockIdx.x == 0 && threadIdx.x == 0) *fix_cnt = 0;
    int blk = blockIdx.x;                 // b*128 + r*32 + n
    int b = blk >> 7, r = (blk >> 5) & 3, n = blk & 31;
    int d = threadIdx.x;
    double v = (double)rm[(((size_t)b * 64 + d) * 4 + r) * 32 + n];
    double sq = v * v;
    #pragma unroll
    for (int off = 32; off > 0; off >>= 1) sq += __shfl_down(sq, off);
    double tot = __shfl(sq, 0);
    double nv = v / sqrt(tot);
    rmn[(((size_t)b * 4 + r) * 32 + n) * 64 + d] = nv;
    float f = (float)nv;
    _Float16 hi = (_Float16)f;
    size_t gi = ((size_t)b * 128 + r * 32 + n) * 64 + d;
    rhi_g[gi] = hi;
    rlo_g[gi] = (_Float16)(f - (float)hi);
}

// K1: split-f16 MFMA hash + f16 tensor prep (qhf/khf/vhf); XCD-pinned b.
__global__ __launch_bounds__(256, 4) void k_hash(const float* __restrict__ q,
                                                 const float* __restrict__ value,
                                                 const _Float16* __restrict__ rhi_g,
                                                 const _Float16* __restrict__ rlo_g,
                                                 int* __restrict__ h_ws,
                                                 int* __restrict__ fix_cnt,
                                                 int* __restrict__ fix_list,
                                                 _Float16* __restrict__ qhf,
                                                 _Float16* __restrict__ khf,
                                                 _Float16* __restrict__ vhf) {
    __shared__ __align__(16) char smem[36864];
    _Float16* Rhi = (_Float16*)smem;            // [128][72]
    _Float16* Rlo = (_Float16*)(smem + 18432);  // [128][72]
    float*    Sc  = (float*)smem;               // overlay [64][133]

    int xcd = blockIdx.x & 7, slot = blockIdx.x >> 3;   // 128 slots
    int b = xcd * 2 + (slot >> 6), chunk = slot & 63;
    int tid = threadIdx.x;
    int w = tid >> 6, lane = tid & 63, quad = lane >> 4, l15 = lane & 15;

    {   // vhf prep: 64 rows of v -> f16 (streaming, no LDS)
        int row = chunk * 64 + (tid >> 2), sub = tid & 3;
        const float4* vp = (const float4*)(value + ((size_t)(b * L_ + row)) * 64 + sub * 16);
        f16x8 h0, h1;
        #pragma unroll
        for (int c = 0; c < 2; c++) {
            float4 t0 = vp[2 * c], t1 = vp[2 * c + 1];
            f16x8& hd = c ? h1 : h0;
            hd[0]=(_Float16)t0.x; hd[1]=(_Float16)t0.y; hd[2]=(_Float16)t0.z; hd[3]=(_Float16)t0.w;
            hd[4]=(_Float16)t1.x; hd[5]=(_Float16)t1.y; hd[6]=(_Float16)t1.z; hd[7]=(_Float16)t1.w;
        }
        _Float16* dst = vhf + ((size_t)(b * L_ + row)) * 64 + sub * 16;
        *(f16x8*)dst = h0;
        *(f16x8*)(dst + 8) = h1;
    }

    {   // stage R split halves
        int row = tid >> 1, dh = (tid & 1) * 32;
        const _Float16* sh = rhi_g + ((size_t)b * 128 + row) * 64 + dh;
        const _Float16* sl = rlo_g + ((size_t)b * 128 + row) * 64 + dh;
        #pragma unroll
        for (int g = 0; g < 4; g++) {
            *(f16x8*)&Rhi[row * 72 + dh + g * 8] = *(const f16x8*)(sh + g * 8);
            *(f16x8*)&Rlo[row * 72 + dh + g * 8] = *(const f16x8*)(sl + g * 8);
        }
    }

    int qrow = chunk * 64 + w * 16 + l15;
    const float* qp = q + ((size_t)(b * L_ + qrow)) * 64;
    float qv[16];
    #pragma unroll
    for (int kt = 0; kt < 2; kt++) {
        float4 t0 = *(const float4*)(qp + kt * 32 + quad * 8);
        float4 t1 = *(const float4*)(qp + kt * 32 + quad * 8 + 4);
        qv[8*kt+0]=t0.x; qv[8*kt+1]=t0.y; qv[8*kt+2]=t0.z; qv[8*kt+3]=t0.w;
        qv[8*kt+4]=t1.x; qv[8*kt+5]=t1.y; qv[8*kt+6]=t1.z; qv[8*kt+7]=t1.w;
    }
    f16x8 Ahi[2], Alo[2];
    #pragma unroll
    for (int kt = 0; kt < 2; kt++) {
        #pragma unroll
        for (int j = 0; j < 8; j++) {
            _Float16 hi = (_Float16)qv[8*kt+j];
            Ahi[kt][j] = hi;
            Alo[kt][j] = (_Float16)(qv[8*kt+j] - (float)hi);
        }
    }
    {   // qhf (raw f16) + khf (scaled f16)
        float ss = 0.f;
        #pragma unroll
        for (int j = 0; j < 16; j++) ss += qv[j] * qv[j];
        ss += __shfl_xor(ss, 16);
        ss += __shfl_xor(ss, 32);
        float nr = sqrtf(ss); if (nr < 1e-12f) nr = 1e-12f;
        float kscale = 0.125f / nr;
        _Float16* qd = qhf + ((size_t)(b * L_ + qrow)) * 64;
        _Float16* kd = khf + ((size_t)(b * L_ + qrow)) * 64;
        #pragma unroll
        for (int kt = 0; kt < 2; kt++) {
            *(f16x8*)(qd + kt * 32 + quad * 8) = Ahi[kt];
            f16x8 hv;
            #pragma unroll
            for (int j = 0; j < 8; j++) hv[j] = (_Float16)(qv[8*kt+j] * kscale);
            *(f16x8*)(kd + kt * 32 + quad * 8) = hv;
        }
    }
    __syncthreads();

    f32x4 acc[8];
    #pragma unroll
    for (int jt = 0; jt < 8; jt++) acc[jt] = (f32x4){0.f, 0.f, 0.f, 0.f};
    #pragma unroll
    for (int jt = 0; jt < 8; jt++) {
        #pragma unroll
        for (int kt = 0; kt < 2; kt++) {
            f16x8 bh = *(const f16x8*)&Rhi[(jt * 16 + l15) * 72 + kt * 32 + quad * 8];
            f16x8 bl = *(const f16x8*)&Rlo[(jt * 16 + l15) * 72 + kt * 32 + quad * 8];
            acc[jt] = __builtin_amdgcn_mfma_f32_16x16x32_f16(Ahi[kt], bh, acc[jt], 0, 0, 0);
            acc[jt] = __builtin_amdgcn_mfma_f32_16x16x32_f16(Ahi[kt], bl, acc[jt], 0, 0, 0);
            acc[jt] = __builtin_amdgcn_mfma_f32_16x16x32_f16(Alo[kt], bh, acc[jt], 0, 0, 0);
        }
    }
    __syncthreads();

    #pragma unroll
    for (int jt = 0; jt < 8; jt++) {
        #pragma unroll
        for (int reg = 0; reg < 4; reg++)
            Sc[(w * 16 + quad * 4 + reg) * 133 + jt * 16 + l15] = acc[jt][reg];
    }
    __syncthreads();

    {
        int row = tid & 63, r = tid >> 6;
        const float* sp = &Sc[row * 133 + r * 32];
        float bp = -1e30f, bn = -1e30f; int ip = 0, in2 = 0;
        float v1 = -1e30f, v2 = -1e30f;
        #pragma unroll
        for (int n = 0; n < 32; n++) {
            float v = sp[n], nv = -v;
            if (v > bp)  { bp = v;  ip = n; }
            if (nv > bn) { bn = nv; in2 = n; }
            if (v > v1)       { v2 = v1; v1 = v; }
            else if (v > v2)  { v2 = v; }
            if (nv > v1)      { v2 = v1; v1 = nv; }
            else if (nv > v2) { v2 = nv; }
        }
        int i1 = (bp >= bn) ? ip : (32 + in2);
        int l = chunk * 64 + row;
        h_ws[((size_t)(b * 4 + r)) * L_ + l] = i1;
        if (v1 - v2 < 4e-5f) {
            int slot2 = atomicAdd(fix_cnt, 1);
            if (slot2 < FIXCAP) fix_list[slot2] = (b << 14) | (r << 12) | l;
        }
    }
}

// K1b: exact fp64 resolve, one wave per flagged row.
__global__ __launch_bounds__(64) void k_fix(const float* __restrict__ q,
                                            const double* __restrict__ rmn,
                                            const int* __restrict__ fix_cnt,
                                            const int* __restrict__ fix_list,
                                            int* __restrict__ h_ws) {
    int cnt = *fix_cnt; if (cnt > FIXCAP) cnt = FIXCAP;
    int lane = threadIdx.x;
    for (int i = blockIdx.x; i < cnt; i += gridDim.x) {
        int e = fix_list[i];
        int b = e >> 14, r = (e >> 12) & 3, l = e & 4095;
        int n = lane & 31;
        const double* rp = rmn + ((size_t)(b * 4 + r)) * 2048 + n * 64;
        const float* qr = q + ((size_t)(b * L_ + l)) * 64;
        double a0 = 0.0, a1 = 0.0, a2 = 0.0, a3 = 0.0;
        #pragma unroll
        for (int d = 0; d < 64; d += 4) {
            a0 += (double)qr[d]   * rp[d];
            a1 += (double)qr[d+1] * rp[d+1];
            a2 += (double)qr[d+2] * rp[d+2];
            a3 += (double)qr[d+3] * rp[d+3];
        }
        double acc = ((a0 + a1) + (a2 + a3));
        double v = (lane < 32) ? acc : -acc;
        int idx = lane;
        #pragma unroll
        for (int off = 1; off < 64; off <<= 1) {
            double ov = __shfl_xor(v, off);
            int   oidx = __shfl_xor(idx, off);
            if (ov > v || (ov == v && oidx < idx)) { v = ov; idx = oidx; }
        }
        if (lane == 0) h_ws[((size_t)(b * 4 + r)) * L_ + l] = idx;
    }
}

// K2: stable counting sort per (b,r)
__global__ __launch_bounds__(64) void k_sort(const int* __restrict__ h_ws,
                                             int* __restrict__ hi_ws,
                                             int* __restrict__ oi_ws) {
    __shared__ int hs[64 * 65];
    __shared__ int cnt[64 * 65];
    int br = blockIdx.x;
    const int* hp = h_ws + (size_t)br * L_;
    int t = threadIdx.x;
    for (int w = 0; w < 64; w++) hs[w * 65 + t] = hp[w * 64 + t];
    for (int u = 0; u < 64; u++) cnt[t * 65 + u] = 0;
    __syncthreads();
    for (int k = 0; k < 64; k++) cnt[t * 65 + hs[t * 65 + k]]++;
    __syncthreads();
    int cs = 0;
    for (int c = 0; c < 64; c++) cs += cnt[c * 65 + t];
    int v = cs;
    #pragma unroll
    for (int off = 1; off < 64; off <<= 1) {
        int u = __shfl_up(v, off);
        if (t >= off) v += u;
    }
    int running = v - cs;
    for (int c = 0; c < 64; c++) {
        int tmp = cnt[c * 65 + t];
        cnt[c * 65 + t] = running;
        running += tmp;
    }
    __syncthreads();
    int* hi = hi_ws + (size_t)br * L_;
    int* oi = oi_ws + (size_t)br * L_;
    for (int k = 0; k < 64; k++) {
        int idx = t * 64 + k;
        int b2 = hs[t * 65 + k];
        int pos = cnt[t * 65 + b2]++;
        hi[pos] = idx;
        oi[idx] = pos;
    }
}

// K2b: per sorted position meta record
__global__ __launch_bounds__(256) void k_meta(const int* __restrict__ h_ws,
                                              const int* __restrict__ hi_ws,
                                              const int* __restrict__ oi_ws,
                                              int4* __restrict__ meta_ws) {
    int gid = blockIdx.x * 256 + threadIdx.x;
    int br = gid >> 12, spos = gid & 4095;
    int b = br >> 2;
    int p = hi_ws[(size_t)br * L_ + spos];
    int hh = h_ws[(size_t)br * L_ + p];
    int pack = 0, packm1 = 0;
    #pragma unroll
    for (int r2 = 0; r2 < 4; r2++) {
        int bk = oi_ws[((size_t)(b * 4 + r2)) * L_ + p] >> 6;
        pack   |= bk << (8 * r2);
        packm1 |= ((bk + 63) & 63) << (8 * r2);
    }
    meta_ws[(size_t)br * L_ + spos] = make_int4(hh, p, pack, packm1);
}

// K3: MFMA fused attention. Direct-global K/Q frags; Vt conflict-free staging;
// standalone Ph buffer (2 barriers); XCD-pinned b; attn layout [B][L][R][64].
__global__ __launch_bounds__(256, 4) void k_attn(const _Float16* __restrict__ qhf,
                                                 const _Float16* __restrict__ khf,
                                                 const _Float16* __restrict__ vhf,
                                                 const int4* __restrict__ meta_ws,
                                                 float* __restrict__ lse_ws,
                                                 _Float16* __restrict__ attn_ws) {
    __shared__ _Float16 Ph[64 * 136];     // 17408 B
    __shared__ _Float16 Vt[64 * 136];     // 17408 B
    __shared__ int4 kmeta[128];           // 2048 B

    int xcd = blockIdx.x & 7, slot = blockIdx.x >> 3;
    int b = xcd * 2 + (slot >> 8);
    int rem = slot & 255, n = rem >> 2, r = rem & 3;
    int tid = threadIdx.x;
    int w = tid >> 6, lane = tid & 63, quad = lane >> 4, l15 = lane & 15;
    int hibase = (b * 4 + r) * L_;

    if (tid < 128) {
        int nprev = (n + 63) & 63;
        int spos = (tid < 64) ? (nprev * 64 + tid) : (n * 64 + (tid - 64));
        kmeta[tid] = meta_ws[hibase + spos];
    }
    __syncthreads();

    // per-lane gather positions
    int kp8[8];
    #pragma unroll
    for (int jt = 0; jt < 8; jt++) kp8[jt] = kmeta[jt * 16 + l15].y;
    int qpos = kmeta[64 + w * 16 + l15].y;

    {   // stage V^T: wave = d-quarter, lane = row-pair -> bank = (4d+lane)%32, 2-way free
        int p0 = kmeta[2 * lane].y, p1 = kmeta[2 * lane + 1].y;
        const _Float16* v0 = vhf + ((size_t)(b * L_ + p0)) * 64 + w * 16;
        const _Float16* v1 = vhf + ((size_t)(b * L_ + p1)) * 64 + w * 16;
        f16x8 a00 = *(const f16x8*)v0, a01 = *(const f16x8*)(v0 + 8);
        f16x8 a10 = *(const f16x8*)v1, a11 = *(const f16x8*)(v1 + 8);
        #pragma unroll
        for (int d = 0; d < 8; d++) {
            f16x2 hv = { a00[d], a10[d] };
            *(f16x2*)&Vt[(w * 16 + d) * 136 + 2 * lane] = hv;
            f16x2 hw = { a01[d], a11[d] };
            *(f16x2*)&Vt[(w * 16 + 8 + d) * 136 + 2 * lane] = hw;
        }
    }

    // Q A-frags (gathered 16B loads)
    const _Float16* qp = qhf + ((size_t)(b * L_ + qpos)) * 64;
    f16x8 afr[2];
    afr[0] = *(const f16x8*)(qp + quad * 8);
    afr[1] = *(const f16x8*)(qp + 32 + quad * 8);

    // QK: K B-frags direct from khf (gathered 16B loads, L1/L2-hot)
    f32x4 acc[8];
    #pragma unroll
    for (int jt = 0; jt < 8; jt++) acc[jt] = (f32x4){0.f, 0.f, 0.f, 0.f};
    #pragma unroll
    for (int jt = 0; jt < 8; jt++) {
        const _Float16* kpp = khf + ((size_t)(b * L_ + kp8[jt])) * 64 + quad * 8;
        f16x8 b0 = *(const f16x8*)kpp;
        f16x8 b1 = *(const f16x8*)(kpp + 32);
        acc[jt] = __builtin_amdgcn_mfma_f32_16x16x32_f16(afr[0], b0, acc[jt], 0, 0, 0);
        acc[jt] = __builtin_amdgcn_mfma_f32_16x16x32_f16(afr[1], b1, acc[jt], 0, 0, 0);
    }

    int4 qm4[4], km4[8];
    #pragma unroll
    for (int reg = 0; reg < 4; reg++) qm4[reg] = kmeta[64 + w * 16 + quad * 4 + reg];
    #pragma unroll
    for (int jt = 0; jt < 8; jt++) km4[jt] = kmeta[jt * 16 + l15];

    float lse_r[4];
    #pragma unroll
    for (int reg = 0; reg < 4; reg++) {
        float s[8];
        #pragma unroll
        for (int jt = 0; jt < 8; jt++) {
            float v = acc[jt][reg];
            if (km4[jt].x != qm4[reg].x) v = -1e9f;
            if (qm4[reg].y < km4[jt].y)  v = -1e9f;
            if (qm4[reg].y == km4[jt].y) v = -1e5f;
            s[jt] = v;
        }
        float m = s[0];
        #pragma unroll
        for (int jt = 1; jt < 8; jt++) m = fmaxf(m, s[jt]);
        #pragma unroll
        for (int off = 1; off < 16; off <<= 1) m = fmaxf(m, __shfl_xor(m, off));
        float te[8], sum = 0.f;
        #pragma unroll
        for (int jt = 0; jt < 8; jt++) { te[jt] = __expf(s[jt] - m); sum += te[jt]; }
        #pragma unroll
        for (int off = 1; off < 16; off <<= 1) sum += __shfl_xor(sum, off);
        float inv = __builtin_amdgcn_rcpf(sum);
        lse_r[reg] = m + __logf(sum);
        int i = w * 16 + quad * 4 + reg;
        #pragma unroll
        for (int jt = 0; jt < 8; jt++) {
            int z1 = km4[jt].z ^ qm4[reg].z;
            int z2 = km4[jt].z ^ qm4[reg].w;
            int nz = __popc((z1 + 0x7f7f7f7f) & 0x80808080)
                   + __popc((z2 + 0x7f7f7f7f) & 0x80808080);
            float p = te[jt] * inv * __builtin_amdgcn_rcpf((float)(8 - nz));
            Ph[i * 136 + jt * 16 + l15] = (_Float16)p;
        }
    }
    if (l15 == 0) {
        #pragma unroll
        for (int reg = 0; reg < 4; reg++)
            lse_ws[hibase + qm4[reg].y] = lse_r[reg];
    }
    __syncthreads();                      // Ph + Vt complete

    f32x4 oacc[4];
    #pragma unroll
    for (int nt = 0; nt < 4; nt++) oacc[nt] = (f32x4){0.f, 0.f, 0.f, 0.f};
    #pragma unroll
    for (int kt = 0; kt < 4; kt++) {
        f16x8 pa = *(const f16x8*)&Ph[(w * 16 + l15) * 136 + kt * 32 + quad * 8];
        #pragma unroll
        for (int nt = 0; nt < 4; nt++) {
            f16x8 vb = *(const f16x8*)&Vt[(nt * 16 + l15) * 136 + kt * 32 + quad * 8];
            oacc[nt] = __builtin_amdgcn_mfma_f32_16x16x32_f16(pa, vb, oacc[nt], 0, 0, 0);
        }
    }
    #pragma unroll
    for (int reg = 0; reg < 4; reg++) {
        size_t base = (((size_t)(b * L_ + qm4[reg].y)) * 4 + r) * 64;   // [b][l][r][64]
        #pragma unroll
        for (int nt = 0; nt < 4; nt++)
            attn_ws[base + nt * 16 + l15] = (_Float16)oacc[nt][reg];
    }
}

// K4a: per (b,r) softmax-over-L stats of lse
__global__ __launch_bounds__(256) void k_rw(const float* __restrict__ lse_ws,
                                            float* __restrict__ rwmax,
                                            float* __restrict__ rwsum) {
    __shared__ float  red[256];
    __shared__ double redd[256];
    int br = blockIdx.x;
    const float* lp = lse_ws + (size_t)br * L_;
    int t = threadIdx.x;
    float m = -1e30f;
    for (int k = t; k < L_; k += 256) m = fmaxf(m, lp[k]);
    red[t] = m; __syncthreads();
    for (int s2 = 128; s2 > 0; s2 >>= 1) {
        if (t < s2) red[t] = fmaxf(red[t], red[t + s2]);
        __syncthreads();
    }
    float mm = red[0];
    double s = 0.0;
    for (int k = t; k < L_; k += 256) s += (double)expf(lp[k] - mm);
    redd[t] = s; __syncthreads();
    for (int s2 = 128; s2 > 0; s2 >>= 1) {
        if (t < s2) redd[t] += redd[t + s2];
        __syncthreads();
    }
    if (t == 0) { rwmax[br] = mm; rwsum[br] = (float)redd[0]; }
}

// K4b: combine. XCD-pinned b; attn [B][L][R][64] -> 512 B contiguous per row.
__global__ __launch_bounds__(256) void k_out(const _Float16* __restrict__ attn_ws,
                                             const float* __restrict__ lse_ws,
                                             const float* __restrict__ rwmax,
                                             const float* __restrict__ rwsum,
                                             float* __restrict__ out) {
    int xcd = blockIdx.x & 7, slot = blockIdx.x >> 3;   // 256 slots
    int b = xcd * 2 + (slot >> 7);
    int inner = slot & 127;                              // 32 rows per block
    int tid = threadIdx.x;
    int l = inner * 32 + (tid >> 3), g = tid & 7;
    size_t row = (size_t)b * L_ + l;
    float o[8];
    #pragma unroll
    for (int k = 0; k < 8; k++) o[k] = 0.f;
    #pragma unroll
    for (int r = 0; r < 4; r++) {
        int br = b * 4 + r;
        float wgt = __expf(lse_ws[(size_t)br * L_ + l] - rwmax[br])
                  * __builtin_amdgcn_rcpf(rwsum[br]);
        f16x8 av = *(const f16x8*)&attn_ws[(row * 4 + r) * 64 + g * 8];
        #pragma unroll
        for (int k = 0; k < 8; k++) o[k] += (float)av[k] * wgt;
    }
    float4* op = (float4*)(out + row * 64 + g * 8);
    op[0] = make_float4(o[0], o[1], o[2], o[3]);
    op[1] = make_float4(o[4], o[5], o[6], o[7]);
}

extern "C" void kernel_launch(void* const* d_in, const int* in_sizes, int n_in,
                              void* d_out, int out_size, void* d_ws, size_t ws_size,
                              hipStream_t stream) {
    const float* query = (const float*)d_in[0];
    const float* value = (const float*)d_in[1];
    const float* rm    = (const float*)d_in[2];
    char* ws = (char*)d_ws;
    double*    rmn    = (double*)ws;
    int*       h_ws   = (int*)(ws + ((size_t)1 << 20));
    int*       hi_ws  = (int*)(ws + ((size_t)2 << 20));
    int*       oi_ws  = (int*)(ws + ((size_t)3 << 20));
    float*     lse_ws = (float*)(ws + ((size_t)4 << 20));
    float*     rwmax  = (float*)(ws + ((size_t)5 << 20));
    float*     rwsum  = (float*)(ws + ((size_t)5 << 20) + 256);
    int*       fix_cnt= (int*)(ws + ((size_t)5 << 20) + 512);
    int*       fix_list=(int*)(ws + ((size_t)5 << 20) + 1024);
    _Float16*  attn_ws= (_Float16*)(ws + ((size_t)6 << 20));
    _Float16*  rhi_g  = (_Float16*)(ws + ((size_t)40 << 20));
    _Float16*  rlo_g  = (_Float16*)(ws + ((size_t)40 << 20) + ((size_t)1 << 19));
    int4*      meta_ws= (int4*)(ws + ((size_t)41 << 20));
    _Float16*  qhf    = (_Float16*)(ws + ((size_t)45 << 20));
    _Float16*  khf    = (_Float16*)(ws + ((size_t)53 << 20));
    _Float16*  vhf    = (_Float16*)(ws + ((size_t)61 << 20));
    float*     out    = (float*)d_out;

    hipLaunchKernelGGL(k_rmnorm, dim3(2048), dim3(64),  0, stream, rm, rmn, rhi_g, rlo_g, fix_cnt);
    hipLaunchKernelGGL(k_hash,   dim3(1024), dim3(256), 0, stream, query, value, rhi_g, rlo_g,
                       h_ws, fix_cnt, fix_list, qhf, khf, vhf);
    hipLaunchKernelGGL(k_fix,    dim3(64),   dim3(64),  0, stream, query, rmn,
                       fix_cnt, fix_list, h_ws);
    hipLaunchKernelGGL(k_sort,   dim3(64),   dim3(64),  0, stream, h_ws, hi_ws, oi_ws);
    hipLaunchKernelGGL(k_meta,   dim3(1024), dim3(256), 0, stream, h_ws, hi_ws, oi_ws, meta_ws);
    hipLaunchKernelGGL(k_attn,   dim3(4096), dim3(256), 0, stream,
                       qhf, khf, vhf, meta_ws, lse_ws, attn_ws);
    hipLaunchKernelGGL(k_rw,     dim3(64),   dim3(256), 0, stream, lse_ws, rwmax, rwsum);
    hipLaunchKernelGGL(k_out,    dim3(2048), dim3(256), 0, stream,
                       attn_ws, lse_ws, rwmax, rwsum, out);
}

// Round 10
// 169.844 us; speedup vs baseline: 1.0682x; 1.0682x over previous
//
#include <hip/hip_runtime.h>
#include <math.h>

#define B_  16
#define L_  4096
#define D_  64
#define R_  4
#define NB_ 64
#define BL_ 64
#define FIXCAP 8192

typedef _Float16 f16x8 __attribute__((ext_vector_type(8)));
typedef _Float16 f16x2 __attribute__((ext_vector_type(2)));
typedef float    f32x4 __attribute__((ext_vector_type(4)));

// ---------------- ws layout ----------------
// [0MB,1MB)     rmn    double   [B][R][32][64]
// [1MB,2MB)     h      int      [B][R][L]
// [2MB,3MB)     hi     int      [B][R][L]
// [3MB,4MB)     oi     int      [B][R][L]
// [4MB,5MB)     lse    float    [B][R][L]   (original index)
// [5MB,+256)    rwmax float[64]; [+256,+512) rwsum; [+512] fix_cnt; [+1024,) fix_list
// [6MB,40MB)    attn   _Float16 [B][L][R][64]  (original index, round-minor)
// [40MB,+256K)  rhi    _Float16 [B][128][64]
// [40.5MB,+256K)rlo    _Float16 [B][128][64]
// [41MB,45MB)   meta   int4     [B*R][L]
// [45MB,53MB)   qhf    _Float16 [B][L][64]   raw q, f16
// [53MB,61MB)   khf    _Float16 [B][L][64]   q/||q||/8, f16
// [61MB,69MB)   vhf    _Float16 [B][L][64]   v, f16

// K0: normalize rand_matrix along d, store fp64 + split-f16 copies; zero fix_cnt.
__global__ __launch_bounds__(64) void k_rmnorm(const float* __restrict__ rm,
                                               double* __restrict__ rmn,
                                               _Float16* __restrict__ rhi_g,
                                               _Float16* __restrict__ rlo_g,
                                               int* __restrict__ fix_cnt) {
    if (blockIdx.x == 0 && threadIdx.x == 0) *fix_cnt = 0;
    int blk = blockIdx.x;                 // b*128 + r*32 + n
    int b = blk >> 7, r = (blk >> 5) & 3, n = blk & 31;
    int d = threadIdx.x;
    double v = (double)rm[(((size_t)b * 64 + d) * 4 + r) * 32 + n];
    double sq = v * v;
    #pragma unroll
    for (int off = 32; off > 0; off >>= 1) sq += __shfl_down(sq, off);
    double tot = __shfl(sq, 0);
    double nv = v / sqrt(tot);
    rmn[(((size_t)b * 4 + r) * 32 + n) * 64 + d] = nv;
    float f = (float)nv;
    _Float16 hi = (_Float16)f;
    size_t gi = ((size_t)b * 128 + r * 32 + n) * 64 + d;
    rhi_g[gi] = hi;
    rlo_g[gi] = (_Float16)(f - (float)hi);
}

// K1: split-f16 MFMA hash + f16 tensor prep (qhf/khf/vhf); XCD-pinned b.
__global__ __launch_bounds__(256, 4) void k_hash(const float* __restrict__ q,
                                                 const float* __restrict__ value,
                                                 const _Float16* __restrict__ rhi_g,
                                                 const _Float16* __restrict__ rlo_g,
                                                 int* __restrict__ h_ws,
                                                 int* __restrict__ fix_cnt,
                                                 int* __restrict__ fix_list,
                                                 _Float16* __restrict__ qhf,
                                                 _Float16* __restrict__ khf,
                                                 _Float16* __restrict__ vhf) {
    __shared__ __align__(16) char smem[36864];
    _Float16* Rhi = (_Float16*)smem;            // [128][72]
    _Float16* Rlo = (_Float16*)(smem + 18432);  // [128][72]
    float*    Sc  = (float*)smem;               // overlay [64][133]

    int xcd = blockIdx.x & 7, slot = blockIdx.x >> 3;   // 128 slots
    int b = xcd * 2 + (slot >> 6), chunk = slot & 63;
    int tid = threadIdx.x;
    int w = tid >> 6, lane = tid & 63, quad = lane >> 4, l15 = lane & 15;

    {   // vhf prep: 64 rows of v -> f16 (streaming, no LDS)
        int row = chunk * 64 + (tid >> 2), sub = tid & 3;
        const float4* vp = (const float4*)(value + ((size_t)(b * L_ + row)) * 64 + sub * 16);
        f16x8 h0, h1;
        #pragma unroll
        for (int c = 0; c < 2; c++) {
            float4 t0 = vp[2 * c], t1 = vp[2 * c + 1];
            f16x8& hd = c ? h1 : h0;
            hd[0]=(_Float16)t0.x; hd[1]=(_Float16)t0.y; hd[2]=(_Float16)t0.z; hd[3]=(_Float16)t0.w;
            hd[4]=(_Float16)t1.x; hd[5]=(_Float16)t1.y; hd[6]=(_Float16)t1.z; hd[7]=(_Float16)t1.w;
        }
        _Float16* dst = vhf + ((size_t)(b * L_ + row)) * 64 + sub * 16;
        *(f16x8*)dst = h0;
        *(f16x8*)(dst + 8) = h1;
    }

    {   // stage R split halves
        int row = tid >> 1, dh = (tid & 1) * 32;
        const _Float16* sh = rhi_g + ((size_t)b * 128 + row) * 64 + dh;
        const _Float16* sl = rlo_g + ((size_t)b * 128 + row) * 64 + dh;
        #pragma unroll
        for (int g = 0; g < 4; g++) {
            *(f16x8*)&Rhi[row * 72 + dh + g * 8] = *(const f16x8*)(sh + g * 8);
            *(f16x8*)&Rlo[row * 72 + dh + g * 8] = *(const f16x8*)(sl + g * 8);
        }
    }

    int qrow = chunk * 64 + w * 16 + l15;
    const float* qp = q + ((size_t)(b * L_ + qrow)) * 64;
    float qv[16];
    #pragma unroll
    for (int kt = 0; kt < 2; kt++) {
        float4 t0 = *(const float4*)(qp + kt * 32 + quad * 8);
        float4 t1 = *(const float4*)(qp + kt * 32 + quad * 8 + 4);
        qv[8*kt+0]=t0.x; qv[8*kt+1]=t0.y; qv[8*kt+2]=t0.z; qv[8*kt+3]=t0.w;
        qv[8*kt+4]=t1.x; qv[8*kt+5]=t1.y; qv[8*kt+6]=t1.z; qv[8*kt+7]=t1.w;
    }
    f16x8 Ahi[2], Alo[2];
    #pragma unroll
    for (int kt = 0; kt < 2; kt++) {
        #pragma unroll
        for (int j = 0; j < 8; j++) {
            _Float16 hi = (_Float16)qv[8*kt+j];
            Ahi[kt][j] = hi;
            Alo[kt][j] = (_Float16)(qv[8*kt+j] - (float)hi);
        }
    }
    {   // qhf (raw f16) + khf (scaled f16)
        float ss = 0.f;
        #pragma unroll
        for (int j = 0; j < 16; j++) ss += qv[j] * qv[j];
        ss += __shfl_xor(ss, 16);
        ss += __shfl_xor(ss, 32);
        float nr = sqrtf(ss); if (nr < 1e-12f) nr = 1e-12f;
        float kscale = 0.125f / nr;
        _Float16* qd = qhf + ((size_t)(b * L_ + qrow)) * 64;
        _Float16* kd = khf + ((size_t)(b * L_ + qrow)) * 64;
        #pragma unroll
        for (int kt = 0; kt < 2; kt++) {
            *(f16x8*)(qd + kt * 32 + quad * 8) = Ahi[kt];
            f16x8 hv;
            #pragma unroll
            for (int j = 0; j < 8; j++) hv[j] = (_Float16)(qv[8*kt+j] * kscale);
            *(f16x8*)(kd + kt * 32 + quad * 8) = hv;
        }
    }
    __syncthreads();

    f32x4 acc[8];
    #pragma unroll
    for (int jt = 0; jt < 8; jt++) acc[jt] = (f32x4){0.f, 0.f, 0.f, 0.f};
    #pragma unroll
    for (int jt = 0; jt < 8; jt++) {
        #pragma unroll
        for (int kt = 0; kt < 2; kt++) {
            f16x8 bh = *(const f16x8*)&Rhi[(jt * 16 + l15) * 72 + kt * 32 + quad * 8];
            f16x8 bl = *(const f16x8*)&Rlo[(jt * 16 + l15) * 72 + kt * 32 + quad * 8];
            acc[jt] = __builtin_amdgcn_mfma_f32_16x16x32_f16(Ahi[kt], bh, acc[jt], 0, 0, 0);
            acc[jt] = __builtin_amdgcn_mfma_f32_16x16x32_f16(Ahi[kt], bl, acc[jt], 0, 0, 0);
            acc[jt] = __builtin_amdgcn_mfma_f32_16x16x32_f16(Alo[kt], bh, acc[jt], 0, 0, 0);
        }
    }
    __syncthreads();

    #pragma unroll
    for (int jt = 0; jt < 8; jt++) {
        #pragma unroll
        for (int reg = 0; reg < 4; reg++)
            Sc[(w * 16 + quad * 4 + reg) * 133 + jt * 16 + l15] = acc[jt][reg];
    }
    __syncthreads();

    {
        int row = tid & 63, r = tid >> 6;
        const float* sp = &Sc[row * 133 + r * 32];
        float bp = -1e30f, bn = -1e30f; int ip = 0, in2 = 0;
        float v1 = -1e30f, v2 = -1e30f;
        #pragma unroll
        for (int n = 0; n < 32; n++) {
            float v = sp[n], nv = -v;
            if (v > bp)  { bp = v;  ip = n; }
            if (nv > bn) { bn = nv; in2 = n; }
            if (v > v1)       { v2 = v1; v1 = v; }
            else if (v > v2)  { v2 = v; }
            if (nv > v1)      { v2 = v1; v1 = nv; }
            else if (nv > v2) { v2 = nv; }
        }
        int i1 = (bp >= bn) ? ip : (32 + in2);
        int l = chunk * 64 + row;
        h_ws[((size_t)(b * 4 + r)) * L_ + l] = i1;
        if (v1 - v2 < 4e-5f) {
            int slot2 = atomicAdd(fix_cnt, 1);
            if (slot2 < FIXCAP) fix_list[slot2] = (b << 14) | (r << 12) | l;
        }
    }
}

// K1b: exact fp64 resolve, one wave per flagged row.
__global__ __launch_bounds__(64) void k_fix(const float* __restrict__ q,
                                            const double* __restrict__ rmn,
                                            const int* __restrict__ fix_cnt,
                                            const int* __restrict__ fix_list,
                                            int* __restrict__ h_ws) {
    int cnt = *fix_cnt; if (cnt > FIXCAP) cnt = FIXCAP;
    int lane = threadIdx.x;
    for (int i = blockIdx.x; i < cnt; i += gridDim.x) {
        int e = fix_list[i];
        int b = e >> 14, r = (e >> 12) & 3, l = e & 4095;
        int n = lane & 31;
        const double* rp = rmn + ((size_t)(b * 4 + r)) * 2048 + n * 64;
        const float* qr = q + ((size_t)(b * L_ + l)) * 64;
        double a0 = 0.0, a1 = 0.0, a2 = 0.0, a3 = 0.0;
        #pragma unroll
        for (int d = 0; d < 64; d += 4) {
            a0 += (double)qr[d]   * rp[d];
            a1 += (double)qr[d+1] * rp[d+1];
            a2 += (double)qr[d+2] * rp[d+2];
            a3 += (double)qr[d+3] * rp[d+3];
        }
        double acc = ((a0 + a1) + (a2 + a3));
        double v = (lane < 32) ? acc : -acc;
        int idx = lane;
        #pragma unroll
        for (int off = 1; off < 64; off <<= 1) {
            double ov = __shfl_xor(v, off);
            int   oidx = __shfl_xor(idx, off);
            if (ov > v || (ov == v && oidx < idx)) { v = ov; idx = oidx; }
        }
        if (lane == 0) h_ws[((size_t)(b * 4 + r)) * L_ + l] = idx;
    }
}

// K2: stable counting sort per (b,r)
__global__ __launch_bounds__(64) void k_sort(const int* __restrict__ h_ws,
                                             int* __restrict__ hi_ws,
                                             int* __restrict__ oi_ws) {
    __shared__ int hs[64 * 65];
    __shared__ int cnt[64 * 65];
    int br = blockIdx.x;
    const int* hp = h_ws + (size_t)br * L_;
    int t = threadIdx.x;
    for (int w = 0; w < 64; w++) hs[w * 65 + t] = hp[w * 64 + t];
    for (int u = 0; u < 64; u++) cnt[t * 65 + u] = 0;
    __syncthreads();
    for (int k = 0; k < 64; k++) cnt[t * 65 + hs[t * 65 + k]]++;
    __syncthreads();
    int cs = 0;
    for (int c = 0; c < 64; c++) cs += cnt[c * 65 + t];
    int v = cs;
    #pragma unroll
    for (int off = 1; off < 64; off <<= 1) {
        int u = __shfl_up(v, off);
        if (t >= off) v += u;
    }
    int running = v - cs;
    for (int c = 0; c < 64; c++) {
        int tmp = cnt[c * 65 + t];
        cnt[c * 65 + t] = running;
        running += tmp;
    }
    __syncthreads();
    int* hi = hi_ws + (size_t)br * L_;
    int* oi = oi_ws + (size_t)br * L_;
    for (int k = 0; k < 64; k++) {
        int idx = t * 64 + k;
        int b2 = hs[t * 65 + k];
        int pos = cnt[t * 65 + b2]++;
        hi[pos] = idx;
        oi[idx] = pos;
    }
}

// K2b: per sorted position meta record
__global__ __launch_bounds__(256) void k_meta(const int* __restrict__ h_ws,
                                              const int* __restrict__ hi_ws,
                                              const int* __restrict__ oi_ws,
                                              int4* __restrict__ meta_ws) {
    int gid = blockIdx.x * 256 + threadIdx.x;
    int br = gid >> 12, spos = gid & 4095;
    int b = br >> 2;
    int p = hi_ws[(size_t)br * L_ + spos];
    int hh = h_ws[(size_t)br * L_ + p];
    int pack = 0, packm1 = 0;
    #pragma unroll
    for (int r2 = 0; r2 < 4; r2++) {
        int bk = oi_ws[((size_t)(b * 4 + r2)) * L_ + p] >> 6;
        pack   |= bk << (8 * r2);
        packm1 |= ((bk + 63) & 63) << (8 * r2);
    }
    meta_ws[(size_t)br * L_ + spos] = make_int4(hh, p, pack, packm1);
}

// K3: MFMA fused attention. K staged in LDS (gathered ops must be staged —
// R9 direct-global B-frags regressed 43->56µs); Vt conflict-free staging;
// Ph overlays Ksh; XCD-pinned b; attn layout [B][L][R][64].
__global__ __launch_bounds__(256, 4) void k_attn(const _Float16* __restrict__ qhf,
                                                 const _Float16* __restrict__ khf,
                                                 const _Float16* __restrict__ vhf,
                                                 const int4* __restrict__ meta_ws,
                                                 float* __restrict__ lse_ws,
                                                 _Float16* __restrict__ attn_ws) {
    __shared__ _Float16 Ksh[128 * 72];    // 18432 B; overlaid by Ph[64][136] (17408 B)
    __shared__ _Float16 Vt[64 * 136];     // 17408 B
    __shared__ int4 kmeta[128];           // 2048 B

    int xcd = blockIdx.x & 7, slot = blockIdx.x >> 3;
    int b = xcd * 2 + (slot >> 8);
    int rem = slot & 255, n = rem >> 2, r = rem & 3;
    int tid = threadIdx.x;
    int w = tid >> 6, lane = tid & 63, quad = lane >> 4, l15 = lane & 15;
    int hibase = (b * 4 + r) * L_;

    if (tid < 128) {
        int nprev = (n + 63) & 63;
        int spos = (tid < 64) ? (nprev * 64 + tid) : (n * 64 + (tid - 64));
        kmeta[tid] = meta_ws[hibase + spos];
    }
    __syncthreads();

    {   // stage K: pure gathered f16 copy, 2 threads per row
        int j = tid >> 1, dh = (tid & 1) * 32;
        const _Float16* src = khf + ((size_t)(b * L_ + kmeta[j].y)) * 64 + dh;
        #pragma unroll
        for (int g = 0; g < 4; g++)
            *(f16x8*)&Ksh[j * 72 + dh + g * 8] = *(const f16x8*)(src + g * 8);
    }
    {   // stage V^T: wave = d-quarter, lane = row-pair -> 2-way bank alias (free)
        int p0 = kmeta[2 * lane].y, p1 = kmeta[2 * lane + 1].y;
        const _Float16* v0 = vhf + ((size_t)(b * L_ + p0)) * 64 + w * 16;
        const _Float16* v1 = vhf + ((size_t)(b * L_ + p1)) * 64 + w * 16;
        f16x8 a00 = *(const f16x8*)v0, a01 = *(const f16x8*)(v0 + 8);
        f16x8 a10 = *(const f16x8*)v1, a11 = *(const f16x8*)(v1 + 8);
        #pragma unroll
        for (int d = 0; d < 8; d++) {
            f16x2 hv = { a00[d], a10[d] };
            *(f16x2*)&Vt[(w * 16 + d) * 136 + 2 * lane] = hv;
            f16x2 hw = { a01[d], a11[d] };
            *(f16x2*)&Vt[(w * 16 + 8 + d) * 136 + 2 * lane] = hw;
        }
    }

    // Q A-frags direct from qhf (coalesced-enough gathered 16B loads, off the
    // critical LDS path)
    int4 qmw = kmeta[64 + w * 16 + l15];
    const _Float16* qp = qhf + ((size_t)(b * L_ + qmw.y)) * 64;
    f16x8 afr[2];
    afr[0] = *(const f16x8*)(qp + quad * 8);
    afr[1] = *(const f16x8*)(qp + 32 + quad * 8);
    __syncthreads();

    f32x4 acc[8];
    #pragma unroll
    for (int jt = 0; jt < 8; jt++) acc[jt] = (f32x4){0.f, 0.f, 0.f, 0.f};
    #pragma unroll
    for (int jt = 0; jt < 8; jt++) {
        #pragma unroll
        for (int kt = 0; kt < 2; kt++) {
            f16x8 bfr = *(const f16x8*)&Ksh[(jt * 16 + l15) * 72 + kt * 32 + quad * 8];
            acc[jt] = __builtin_amdgcn_mfma_f32_16x16x32_f16(afr[kt], bfr, acc[jt], 0, 0, 0);
        }
    }

    int4 qm4[4], km4[8];
    #pragma unroll
    for (int reg = 0; reg < 4; reg++) qm4[reg] = kmeta[64 + w * 16 + quad * 4 + reg];
    #pragma unroll
    for (int jt = 0; jt < 8; jt++) km4[jt] = kmeta[jt * 16 + l15];
    __syncthreads();                      // QK reads of Ksh done -> overlay

    _Float16* Ph = Ksh;                   // [64][136]
    float lse_r[4];
    #pragma unroll
    for (int reg = 0; reg < 4; reg++) {
        float s[8];
        #pragma unroll
        for (int jt = 0; jt < 8; jt++) {
            float v = acc[jt][reg];
            if (km4[jt].x != qm4[reg].x) v = -1e9f;
            if (qm4[reg].y < km4[jt].y)  v = -1e9f;
            if (qm4[reg].y == km4[jt].y) v = -1e5f;
            s[jt] = v;
        }
        float m = s[0];
        #pragma unroll
        for (int jt = 1; jt < 8; jt++) m = fmaxf(m, s[jt]);
        #pragma unroll
        for (int off = 1; off < 16; off <<= 1) m = fmaxf(m, __shfl_xor(m, off));
        float te[8], sum = 0.f;
        #pragma unroll
        for (int jt = 0; jt < 8; jt++) { te[jt] = __expf(s[jt] - m); sum += te[jt]; }
        #pragma unroll
        for (int off = 1; off < 16; off <<= 1) sum += __shfl_xor(sum, off);
        float inv = __builtin_amdgcn_rcpf(sum);
        lse_r[reg] = m + __logf(sum);
        int i = w * 16 + quad * 4 + reg;
        #pragma unroll
        for (int jt = 0; jt < 8; jt++) {
            int z1 = km4[jt].z ^ qm4[reg].z;
            int z2 = km4[jt].z ^ qm4[reg].w;
            int nz = __popc((z1 + 0x7f7f7f7f) & 0x80808080)
                   + __popc((z2 + 0x7f7f7f7f) & 0x80808080);
            float p = te[jt] * inv * __builtin_amdgcn_rcpf((float)(8 - nz));
            Ph[i * 136 + jt * 16 + l15] = (_Float16)p;
        }
    }
    if (l15 == 0) {
        #pragma unroll
        for (int reg = 0; reg < 4; reg++)
            lse_ws[hibase + qm4[reg].y] = lse_r[reg];
    }
    __syncthreads();                      // Ph complete

    f32x4 oacc[4];
    #pragma unroll
    for (int nt = 0; nt < 4; nt++) oacc[nt] = (f32x4){0.f, 0.f, 0.f, 0.f};
    #pragma unroll
    for (int kt = 0; kt < 4; kt++) {
        f16x8 pa = *(const f16x8*)&Ph[(w * 16 + l15) * 136 + kt * 32 + quad * 8];
        #pragma unroll
        for (int nt = 0; nt < 4; nt++) {
            f16x8 vb = *(const f16x8*)&Vt[(nt * 16 + l15) * 136 + kt * 32 + quad * 8];
            oacc[nt] = __builtin_amdgcn_mfma_f32_16x16x32_f16(pa, vb, oacc[nt], 0, 0, 0);
        }
    }
    #pragma unroll
    for (int reg = 0; reg < 4; reg++) {
        size_t base = (((size_t)(b * L_ + qm4[reg].y)) * 4 + r) * 64;   // [b][l][r][64]
        #pragma unroll
        for (int nt = 0; nt < 4; nt++)
            attn_ws[base + nt * 16 + l15] = (_Float16)oacc[nt][reg];
    }
}

// K4a: per (b,r) softmax-over-L stats of lse
__global__ __launch_bounds__(256) void k_rw(const float* __restrict__ lse_ws,
                                            float* __restrict__ rwmax,
                                            float* __restrict__ rwsum) {
    __shared__ float  red[256];
    __shared__ double redd[256];
    int br = blockIdx.x;
    const float* lp = lse_ws + (size_t)br * L_;
    int t = threadIdx.x;
    float m = -1e30f;
    for (int k = t; k < L_; k += 256) m = fmaxf(m, lp[k]);
    red[t] = m; __syncthreads();
    for (int s2 = 128; s2 > 0; s2 >>= 1) {
        if (t < s2) red[t] = fmaxf(red[t], red[t + s2]);
        __syncthreads();
    }
    float mm = red[0];
    double s = 0.0;
    for (int k = t; k < L_; k += 256) s += (double)expf(lp[k] - mm);
    redd[t] = s; __syncthreads();
    for (int s2 = 128; s2 > 0; s2 >>= 1) {
        if (t < s2) redd[t] += redd[t + s2];
        __syncthreads();
    }
    if (t == 0) { rwmax[br] = mm; rwsum[br] = (float)redd[0]; }
}

// K4b: combine. XCD-pinned b; attn [B][L][R][64] -> 512 B contiguous per row.
__global__ __launch_bounds__(256) void k_out(const _Float16* __restrict__ attn_ws,
                                             const float* __restrict__ lse_ws,
                                             const float* __restrict__ rwmax,
                                             const float* __restrict__ rwsum,
                                             float* __restrict__ out) {
    int xcd = blockIdx.x & 7, slot = blockIdx.x >> 3;   // 256 slots
    int b = xcd * 2 + (slot >> 7);
    int inner = slot & 127;                              // 32 rows per block
    int tid = threadIdx.x;
    int l = inner * 32 + (tid >> 3), g = tid & 7;
    size_t row = (size_t)b * L_ + l;
    float o[8];
    #pragma unroll
    for (int k = 0; k < 8; k++) o[k] = 0.f;
    #pragma unroll
    for (int r = 0; r < 4; r++) {
        int br = b * 4 + r;
        float wgt = __expf(lse_ws[(size_t)br * L_ + l] - rwmax[br])
                  * __builtin_amdgcn_rcpf(rwsum[br]);
        f16x8 av = *(const f16x8*)&attn_ws[(row * 4 + r) * 64 + g * 8];
        #pragma unroll
        for (int k = 0; k < 8; k++) o[k] += (float)av[k] * wgt;
    }
    float4* op = (float4*)(out + row * 64 + g * 8);
    op[0] = make_float4(o[0], o[1], o[2], o[3]);
    op[1] = make_float4(o[4], o[5], o[6], o[7]);
}

extern "C" void kernel_launch(void* const* d_in, const int* in_sizes, int n_in,
                              void* d_out, int out_size, void* d_ws, size_t ws_size,
                              hipStream_t stream) {
    const float* query = (const float*)d_in[0];
    const float* value = (const float*)d_in[1];
    const float* rm    = (const float*)d_in[2];
    char* ws = (char*)d_ws;
    double*    rmn    = (double*)ws;
    int*       h_ws   = (int*)(ws + ((size_t)1 << 20));
    int*       hi_ws  = (int*)(ws + ((size_t)2 << 20));
    int*       oi_ws  = (int*)(ws + ((size_t)3 << 20));
    float*     lse_ws = (float*)(ws + ((size_t)4 << 20));
    float*     rwmax  = (float*)(ws + ((size_t)5 << 20));
    float*     rwsum  = (float*)(ws + ((size_t)5 << 20) + 256);
    int*       fix_cnt= (int*)(ws + ((size_t)5 << 20) + 512);
    int*       fix_list=(int*)(ws + ((size_t)5 << 20) + 1024);
    _Float16*  attn_ws= (_Float16*)(ws + ((size_t)6 << 20));
    _Float16*  rhi_g  = (_Float16*)(ws + ((size_t)40 << 20));
    _Float16*  rlo_g  = (_Float16*)(ws + ((size_t)40 << 20) + ((size_t)1 << 19));
    int4*      meta_ws= (int4*)(ws + ((size_t)41 << 20));
    _Float16*  qhf    = (_Float16*)(ws + ((size_t)45 << 20));
    _Float16*  khf    = (_Float16*)(ws + ((size_t)53 << 20));
    _Float16*  vhf    = (_Float16*)(ws + ((size_t)61 << 20));
    float*     out    = (float*)d_out;

    hipLaunchKernelGGL(k_rmnorm, dim3(2048), dim3(64),  0, stream, rm, rmn, rhi_g, rlo_g, fix_cnt);
    hipLaunchKernelGGL(k_hash,   dim3(1024), dim3(256), 0, stream, query, value, rhi_g, rlo_g,
                       h_ws, fix_cnt, fix_list, qhf, khf, vhf);
    hipLaunchKernelGGL(k_fix,    dim3(64),   dim3(64),  0, stream, query, rmn,
                       fix_cnt, fix_list, h_ws);
    hipLaunchKernelGGL(k_sort,   dim3(64),   dim3(64),  0, stream, h_ws, hi_ws, oi_ws);
    hipLaunchKernelGGL(k_meta,   dim3(1024), dim3(256), 0, stream, h_ws, hi_ws, oi_ws, meta_ws);
    hipLaunchKernelGGL(k_attn,   dim3(4096), dim3(256), 0, stream,
                       qhf, khf, vhf, meta_ws, lse_ws, attn_ws);
    hipLaunchKernelGGL(k_rw,     dim3(64),   dim3(256), 0, stream, lse_ws, rwmax, rwsum);
    hipLaunchKernelGGL(k_out,    dim3(2048), dim3(256), 0, stream,
                       attn_ws, lse_ws, rwmax, rwsum, out);
}

// Round 11
// 169.761 us; speedup vs baseline: 1.0687x; 1.0005x over previous
//
#include <hip/hip_runtime.h>
#include <math.h>

#define B_  16
#define L_  4096
#define D_  64
#define R_  4
#define NB_ 64
#define BL_ 64
#define FIXCAP 8192

typedef _Float16 f16x8 __attribute__((ext_vector_type(8)));
typedef _Float16 f16x2 __attribute__((ext_vector_type(2)));
typedef float    f32x4 __attribute__((ext_vector_type(4)));

// ---------------- ws layout ----------------
// [0MB,1MB)     rmn    double   [B][R][32][64]
// [1MB,2MB)     h      int      [B][R][L]
// [2MB,3MB)     hi     int      [B][R][L]
// [3MB,4MB)     oi     int      [B][R][L]
// [4MB,5MB)     lse    float    [B][R][L]   (original index)
// [5MB,+256)    rwmax float[64]; [+256,+512) rwsum; [+512] fix_cnt; [+1024,) fix_list
// [6MB,40MB)    attn   _Float16 [B][L][R][64]  (original index, round-minor)
// [40MB,+256K)  rhi    _Float16 [B][128][64]
// [40.5MB,+256K)rlo    _Float16 [B][128][64]
// [41MB,45MB)   meta   int4     [B*R][L]
// [45MB,53MB)   qhf    _Float16 [B][L][64]   raw q, f16
// [53MB,61MB)   khf    _Float16 [B][L][64]   q/||q||/8, f16
// [61MB,69MB)   vhf    _Float16 [B][L][64]   v, f16

// K0: normalize rand_matrix along d, store fp64 + split-f16 copies; zero fix_cnt.
__global__ __launch_bounds__(64) void k_rmnorm(const float* __restrict__ rm,
                                               double* __restrict__ rmn,
                                               _Float16* __restrict__ rhi_g,
                                               _Float16* __restrict__ rlo_g,
                                               int* __restrict__ fix_cnt) {
    if (blockIdx.x == 0 && threadIdx.x == 0) *fix_cnt = 0;
    int blk = blockIdx.x;                 // b*128 + r*32 + n
    int b = blk >> 7, r = (blk >> 5) & 3, n = blk & 31;
    int d = threadIdx.x;
    double v = (double)rm[(((size_t)b * 64 + d) * 4 + r) * 32 + n];
    double sq = v * v;
    #pragma unroll
    for (int off = 32; off > 0; off >>= 1) sq += __shfl_down(sq, off);
    double tot = __shfl(sq, 0);
    double nv = v / sqrt(tot);
    rmn[(((size_t)b * 4 + r) * 32 + n) * 64 + d] = nv;
    float f = (float)nv;
    _Float16 hi = (_Float16)f;
    size_t gi = ((size_t)b * 128 + r * 32 + n) * 64 + d;
    rhi_g[gi] = hi;
    rlo_g[gi] = (_Float16)(f - (float)hi);
}

// K1: split-f16 MFMA hash + f16 tensor prep (qhf/khf/vhf); XCD-pinned b.
__global__ __launch_bounds__(256, 4) void k_hash(const float* __restrict__ q,
                                                 const float* __restrict__ value,
                                                 const _Float16* __restrict__ rhi_g,
                                                 const _Float16* __restrict__ rlo_g,
                                                 int* __restrict__ h_ws,
                                                 int* __restrict__ fix_cnt,
                                                 int* __restrict__ fix_list,
                                                 _Float16* __restrict__ qhf,
                                                 _Float16* __restrict__ khf,
                                                 _Float16* __restrict__ vhf) {
    __shared__ __align__(16) char smem[36864];
    _Float16* Rhi = (_Float16*)smem;            // [128][72]
    _Float16* Rlo = (_Float16*)(smem + 18432);  // [128][72]
    float*    Sc  = (float*)smem;               // overlay [64][133]

    int xcd = blockIdx.x & 7, slot = blockIdx.x >> 3;   // 128 slots
    int b = xcd * 2 + (slot >> 6), chunk = slot & 63;
    int tid = threadIdx.x;
    int w = tid >> 6, lane = tid & 63, quad = lane >> 4, l15 = lane & 15;

    {   // vhf prep: 64 rows of v -> f16 (streaming, no LDS)
        int row = chunk * 64 + (tid >> 2), sub = tid & 3;
        const float4* vp = (const float4*)(value + ((size_t)(b * L_ + row)) * 64 + sub * 16);
        f16x8 h0, h1;
        #pragma unroll
        for (int c = 0; c < 2; c++) {
            float4 t0 = vp[2 * c], t1 = vp[2 * c + 1];
            f16x8& hd = c ? h1 : h0;
            hd[0]=(_Float16)t0.x; hd[1]=(_Float16)t0.y; hd[2]=(_Float16)t0.z; hd[3]=(_Float16)t0.w;
            hd[4]=(_Float16)t1.x; hd[5]=(_Float16)t1.y; hd[6]=(_Float16)t1.z; hd[7]=(_Float16)t1.w;
        }
        _Float16* dst = vhf + ((size_t)(b * L_ + row)) * 64 + sub * 16;
        *(f16x8*)dst = h0;
        *(f16x8*)(dst + 8) = h1;
    }

    {   // stage R split halves
        int row = tid >> 1, dh = (tid & 1) * 32;
        const _Float16* sh = rhi_g + ((size_t)b * 128 + row) * 64 + dh;
        const _Float16* sl = rlo_g + ((size_t)b * 128 + row) * 64 + dh;
        #pragma unroll
        for (int g = 0; g < 4; g++) {
            *(f16x8*)&Rhi[row * 72 + dh + g * 8] = *(const f16x8*)(sh + g * 8);
            *(f16x8*)&Rlo[row * 72 + dh + g * 8] = *(const f16x8*)(sl + g * 8);
        }
    }

    int qrow = chunk * 64 + w * 16 + l15;
    const float* qp = q + ((size_t)(b * L_ + qrow)) * 64;
    float qv[16];
    #pragma unroll
    for (int kt = 0; kt < 2; kt++) {
        float4 t0 = *(const float4*)(qp + kt * 32 + quad * 8);
        float4 t1 = *(const float4*)(qp + kt * 32 + quad * 8 + 4);
        qv[8*kt+0]=t0.x; qv[8*kt+1]=t0.y; qv[8*kt+2]=t0.z; qv[8*kt+3]=t0.w;
        qv[8*kt+4]=t1.x; qv[8*kt+5]=t1.y; qv[8*kt+6]=t1.z; qv[8*kt+7]=t1.w;
    }
    f16x8 Ahi[2], Alo[2];
    #pragma unroll
    for (int kt = 0; kt < 2; kt++) {
        #pragma unroll
        for (int j = 0; j < 8; j++) {
            _Float16 hi = (_Float16)qv[8*kt+j];
            Ahi[kt][j] = hi;
            Alo[kt][j] = (_Float16)(qv[8*kt+j] - (float)hi);
        }
    }
    {   // qhf (raw f16) + khf (scaled f16)
        float ss = 0.f;
        #pragma unroll
        for (int j = 0; j < 16; j++) ss += qv[j] * qv[j];
        ss += __shfl_xor(ss, 16);
        ss += __shfl_xor(ss, 32);
        float nr = sqrtf(ss); if (nr < 1e-12f) nr = 1e-12f;
        float kscale = 0.125f / nr;
        _Float16* qd = qhf + ((size_t)(b * L_ + qrow)) * 64;
        _Float16* kd = khf + ((size_t)(b * L_ + qrow)) * 64;
        #pragma unroll
        for (int kt = 0; kt < 2; kt++) {
            *(f16x8*)(qd + kt * 32 + quad * 8) = Ahi[kt];
            f16x8 hv;
            #pragma unroll
            for (int j = 0; j < 8; j++) hv[j] = (_Float16)(qv[8*kt+j] * kscale);
            *(f16x8*)(kd + kt * 32 + quad * 8) = hv;
        }
    }
    __syncthreads();

    f32x4 acc[8];
    #pragma unroll
    for (int jt = 0; jt < 8; jt++) acc[jt] = (f32x4){0.f, 0.f, 0.f, 0.f};
    #pragma unroll
    for (int jt = 0; jt < 8; jt++) {
        #pragma unroll
        for (int kt = 0; kt < 2; kt++) {
            f16x8 bh = *(const f16x8*)&Rhi[(jt * 16 + l15) * 72 + kt * 32 + quad * 8];
            f16x8 bl = *(const f16x8*)&Rlo[(jt * 16 + l15) * 72 + kt * 32 + quad * 8];
            acc[jt] = __builtin_amdgcn_mfma_f32_16x16x32_f16(Ahi[kt], bh, acc[jt], 0, 0, 0);
            acc[jt] = __builtin_amdgcn_mfma_f32_16x16x32_f16(Ahi[kt], bl, acc[jt], 0, 0, 0);
            acc[jt] = __builtin_amdgcn_mfma_f32_16x16x32_f16(Alo[kt], bh, acc[jt], 0, 0, 0);
        }
    }
    __syncthreads();

    #pragma unroll
    for (int jt = 0; jt < 8; jt++) {
        #pragma unroll
        for (int reg = 0; reg < 4; reg++)
            Sc[(w * 16 + quad * 4 + reg) * 133 + jt * 16 + l15] = acc[jt][reg];
    }
    __syncthreads();

    {
        int row = tid & 63, r = tid >> 6;
        const float* sp = &Sc[row * 133 + r * 32];
        float bp = -1e30f, bn = -1e30f; int ip = 0, in2 = 0;
        float v1 = -1e30f, v2 = -1e30f;
        #pragma unroll
        for (int n = 0; n < 32; n++) {
            float v = sp[n], nv = -v;
            if (v > bp)  { bp = v;  ip = n; }
            if (nv > bn) { bn = nv; in2 = n; }
            if (v > v1)       { v2 = v1; v1 = v; }
            else if (v > v2)  { v2 = v; }
            if (nv > v1)      { v2 = v1; v1 = nv; }
            else if (nv > v2) { v2 = nv; }
        }
        int i1 = (bp >= bn) ? ip : (32 + in2);
        int l = chunk * 64 + row;
        h_ws[((size_t)(b * 4 + r)) * L_ + l] = i1;
        if (v1 - v2 < 4e-5f) {
            int slot2 = atomicAdd(fix_cnt, 1);
            if (slot2 < FIXCAP) fix_list[slot2] = (b << 14) | (r << 12) | l;
        }
    }
}

// K1b: exact fp64 resolve, one wave per flagged row.
__global__ __launch_bounds__(64) void k_fix(const float* __restrict__ q,
                                            const double* __restrict__ rmn,
                                            const int* __restrict__ fix_cnt,
                                            const int* __restrict__ fix_list,
                                            int* __restrict__ h_ws) {
    int cnt = *fix_cnt; if (cnt > FIXCAP) cnt = FIXCAP;
    int lane = threadIdx.x;
    for (int i = blockIdx.x; i < cnt; i += gridDim.x) {
        int e = fix_list[i];
        int b = e >> 14, r = (e >> 12) & 3, l = e & 4095;
        int n = lane & 31;
        const double* rp = rmn + ((size_t)(b * 4 + r)) * 2048 + n * 64;
        const float* qr = q + ((size_t)(b * L_ + l)) * 64;
        double a0 = 0.0, a1 = 0.0, a2 = 0.0, a3 = 0.0;
        #pragma unroll
        for (int d = 0; d < 64; d += 4) {
            a0 += (double)qr[d]   * rp[d];
            a1 += (double)qr[d+1] * rp[d+1];
            a2 += (double)qr[d+2] * rp[d+2];
            a3 += (double)qr[d+3] * rp[d+3];
        }
        double acc = ((a0 + a1) + (a2 + a3));
        double v = (lane < 32) ? acc : -acc;
        int idx = lane;
        #pragma unroll
        for (int off = 1; off < 64; off <<= 1) {
            double ov = __shfl_xor(v, off);
            int   oidx = __shfl_xor(idx, off);
            if (ov > v || (ov == v && oidx < idx)) { v = ov; idx = oidx; }
        }
        if (lane == 0) h_ws[((size_t)(b * 4 + r)) * L_ + l] = idx;
    }
}

// K2: stable counting sort per (b,r) — 256 threads, 256 sub-chunks of 16.
__global__ __launch_bounds__(256) void k_sort(const int* __restrict__ h_ws,
                                              int* __restrict__ hi_ws,
                                              int* __restrict__ oi_ws) {
    __shared__ unsigned short hs16[4096];        // 8 KB
    __shared__ unsigned short cnt[256 * 66];     // 33.8 KB (pad 66)
    __shared__ int partial[4 * 64];
    __shared__ int baseb[64];
    int br = blockIdx.x;
    const int* hp = h_ws + (size_t)br * L_;
    int t = threadIdx.x;
    for (int k = t; k < 4096; k += 256) hs16[k] = (unsigned short)hp[k];
    for (int k = t; k < 256 * 66; k += 256) cnt[k] = 0;
    __syncthreads();
    {   // count: thread owns sub t (16 elements), no atomics
        unsigned short* row = &cnt[t * 66];
        int base = t * 16;
        #pragma unroll
        for (int k = 0; k < 16; k++) row[hs16[base + k]]++;
    }
    __syncthreads();
    {   // group partial sums per bucket: thread (u = t&63, g = t>>6)
        int u = t & 63, g = t >> 6;
        int s = 0;
        for (int c = g * 64; c < g * 64 + 64; c++) s += cnt[c * 66 + u];
        partial[g * 64 + u] = s;
    }
    __syncthreads();
    if (t < 64) {                                // totals + exclusive scan (wave 0)
        int tot = partial[t] + partial[64 + t] + partial[128 + t] + partial[192 + t];
        int v = tot;
        #pragma unroll
        for (int off = 1; off < 64; off <<= 1) {
            int u2 = __shfl_up(v, off);
            if (t >= off) v += u2;
        }
        baseb[t] = v - tot;
    }
    __syncthreads();
    {   // per-sub running offsets: thread (u,g)
        int u = t & 63, g = t >> 6;
        int running = baseb[u];
        for (int gg = 0; gg < g; gg++) running += partial[gg * 64 + u];
        for (int c = g * 64; c < g * 64 + 64; c++) {
            int tmp = cnt[c * 66 + u];
            cnt[c * 66 + u] = (unsigned short)running;   // positions < 4096, fits u16
            running += tmp;
        }
    }
    __syncthreads();
    {   // placement: thread = sub t, stable (subs in order, serial within sub)
        int* hi = hi_ws + (size_t)br * L_;
        int* oi = oi_ws + (size_t)br * L_;
        unsigned short* row = &cnt[t * 66];
        int base = t * 16;
        #pragma unroll
        for (int k = 0; k < 16; k++) {
            int idx = base + k;
            int bucket = hs16[idx];
            int pos = row[bucket]++;
            hi[pos] = idx;
            oi[idx] = pos;
        }
    }
}

// K2b: per sorted position meta record
__global__ __launch_bounds__(256) void k_meta(const int* __restrict__ h_ws,
                                              const int* __restrict__ hi_ws,
                                              const int* __restrict__ oi_ws,
                                              int4* __restrict__ meta_ws) {
    int gid = blockIdx.x * 256 + threadIdx.x;
    int br = gid >> 12, spos = gid & 4095;
    int b = br >> 2;
    int p = hi_ws[(size_t)br * L_ + spos];
    int hh = h_ws[(size_t)br * L_ + p];
    int pack = 0, packm1 = 0;
    #pragma unroll
    for (int r2 = 0; r2 < 4; r2++) {
        int bk = oi_ws[((size_t)(b * 4 + r2)) * L_ + p] >> 6;
        pack   |= bk << (8 * r2);
        packm1 |= ((bk + 63) & 63) << (8 * r2);
    }
    meta_ws[(size_t)br * L_ + spos] = make_int4(hh, p, pack, packm1);
}

// K3: MFMA fused attention. K staged in LDS (stride 76: kills 4-way staging-write
// conflicts); Vt conflict-free; Ph overlays Ksh; XCD-pinned; attn [B][L][R][64].
__global__ __launch_bounds__(256, 4) void k_attn(const _Float16* __restrict__ qhf,
                                                 const _Float16* __restrict__ khf,
                                                 const _Float16* __restrict__ vhf,
                                                 const int4* __restrict__ meta_ws,
                                                 float* __restrict__ lse_ws,
                                                 _Float16* __restrict__ attn_ws) {
    __shared__ _Float16 Ksh[128 * 76];    // 19456 B; overlaid by Ph[64][136] (17408 B)
    __shared__ _Float16 Vt[64 * 136];     // 17408 B
    __shared__ int4 kmeta[128];           // 2048 B

    int xcd = blockIdx.x & 7, slot = blockIdx.x >> 3;
    int b = xcd * 2 + (slot >> 8);
    int rem = slot & 255, n = rem >> 2, r = rem & 3;
    int tid = threadIdx.x;
    int w = tid >> 6, lane = tid & 63, quad = lane >> 4, l15 = lane & 15;
    int hibase = (b * 4 + r) * L_;

    if (tid < 128) {
        int nprev = (n + 63) & 63;
        int spos = (tid < 64) ? (nprev * 64 + tid) : (n * 64 + (tid - 64));
        kmeta[tid] = meta_ws[hibase + spos];
    }
    __syncthreads();

    {   // stage K: pure gathered f16 copy, 2 threads per row
        int j = tid >> 1, dh = (tid & 1) * 32;
        const _Float16* src = khf + ((size_t)(b * L_ + kmeta[j].y)) * 64 + dh;
        #pragma unroll
        for (int g = 0; g < 4; g++)
            *(f16x8*)&Ksh[j * 76 + dh + g * 8] = *(const f16x8*)(src + g * 8);
    }
    {   // stage V^T: wave = d-quarter, lane = row-pair -> 2-way bank alias (free)
        int p0 = kmeta[2 * lane].y, p1 = kmeta[2 * lane + 1].y;
        const _Float16* v0 = vhf + ((size_t)(b * L_ + p0)) * 64 + w * 16;
        const _Float16* v1 = vhf + ((size_t)(b * L_ + p1)) * 64 + w * 16;
        f16x8 a00 = *(const f16x8*)v0, a01 = *(const f16x8*)(v0 + 8);
        f16x8 a10 = *(const f16x8*)v1, a11 = *(const f16x8*)(v1 + 8);
        #pragma unroll
        for (int d = 0; d < 8; d++) {
            f16x2 hv = { a00[d], a10[d] };
            *(f16x2*)&Vt[(w * 16 + d) * 136 + 2 * lane] = hv;
            f16x2 hw = { a01[d], a11[d] };
            *(f16x2*)&Vt[(w * 16 + 8 + d) * 136 + 2 * lane] = hw;
        }
    }

    // Q A-frags direct from qhf (off the critical LDS path)
    int4 qmw = kmeta[64 + w * 16 + l15];
    const _Float16* qp = qhf + ((size_t)(b * L_ + qmw.y)) * 64;
    f16x8 afr[2];
    afr[0] = *(const f16x8*)(qp + quad * 8);
    afr[1] = *(const f16x8*)(qp + 32 + quad * 8);
    __syncthreads();

    f32x4 acc[8];
    #pragma unroll
    for (int jt = 0; jt < 8; jt++) acc[jt] = (f32x4){0.f, 0.f, 0.f, 0.f};
    #pragma unroll
    for (int jt = 0; jt < 8; jt++) {
        #pragma unroll
        for (int kt = 0; kt < 2; kt++) {
            f16x8 bfr = *(const f16x8*)&Ksh[(jt * 16 + l15) * 76 + kt * 32 + quad * 8];
            acc[jt] = __builtin_amdgcn_mfma_f32_16x16x32_f16(afr[kt], bfr, acc[jt], 0, 0, 0);
        }
    }

    int4 qm4[4], km4[8];
    #pragma unroll
    for (int reg = 0; reg < 4; reg++) qm4[reg] = kmeta[64 + w * 16 + quad * 4 + reg];
    #pragma unroll
    for (int jt = 0; jt < 8; jt++) km4[jt] = kmeta[jt * 16 + l15];
    __syncthreads();                      // QK reads of Ksh done -> overlay

    _Float16* Ph = Ksh;                   // [64][136]
    float lse_r[4];
    #pragma unroll
    for (int reg = 0; reg < 4; reg++) {
        float s[8];
        #pragma unroll
        for (int jt = 0; jt < 8; jt++) {
            float v = acc[jt][reg];
            if (km4[jt].x != qm4[reg].x) v = -1e9f;
            if (qm4[reg].y < km4[jt].y)  v = -1e9f;
            if (qm4[reg].y == km4[jt].y) v = -1e5f;
            s[jt] = v;
        }
        float m = s[0];
        #pragma unroll
        for (int jt = 1; jt < 8; jt++) m = fmaxf(m, s[jt]);
        #pragma unroll
        for (int off = 1; off < 16; off <<= 1) m = fmaxf(m, __shfl_xor(m, off));
        float te[8], sum = 0.f;
        #pragma unroll
        for (int jt = 0; jt < 8; jt++) { te[jt] = __expf(s[jt] - m); sum += te[jt]; }
        #pragma unroll
        for (int off = 1; off < 16; off <<= 1) sum += __shfl_xor(sum, off);
        float inv = __builtin_amdgcn_rcpf(sum);
        lse_r[reg] = m + __logf(sum);
        int i = w * 16 + quad * 4 + reg;
        #pragma unroll
        for (int jt = 0; jt < 8; jt++) {
            int z1 = km4[jt].z ^ qm4[reg].z;
            int z2 = km4[jt].z ^ qm4[reg].w;
            int nz = __popc((z1 + 0x7f7f7f7f) & 0x80808080)
                   + __popc((z2 + 0x7f7f7f7f) & 0x80808080);
            float p = te[jt] * inv * __builtin_amdgcn_rcpf((float)(8 - nz));
            Ph[i * 136 + jt * 16 + l15] = (_Float16)p;
        }
    }
    if (l15 == 0) {
        #pragma unroll
        for (int reg = 0; reg < 4; reg++)
            lse_ws[hibase + qm4[reg].y] = lse_r[reg];
    }
    __syncthreads();                      // Ph complete

    f32x4 oacc[4];
    #pragma unroll
    for (int nt = 0; nt < 4; nt++) oacc[nt] = (f32x4){0.f, 0.f, 0.f, 0.f};
    #pragma unroll
    for (int kt = 0; kt < 4; kt++) {
        f16x8 pa = *(const f16x8*)&Ph[(w * 16 + l15) * 136 + kt * 32 + quad * 8];
        #pragma unroll
        for (int nt = 0; nt < 4; nt++) {
            f16x8 vb = *(const f16x8*)&Vt[(nt * 16 + l15) * 136 + kt * 32 + quad * 8];
            oacc[nt] = __builtin_amdgcn_mfma_f32_16x16x32_f16(pa, vb, oacc[nt], 0, 0, 0);
        }
    }
    #pragma unroll
    for (int reg = 0; reg < 4; reg++) {
        size_t base = (((size_t)(b * L_ + qm4[reg].y)) * 4 + r) * 64;   // [b][l][r][64]
        #pragma unroll
        for (int nt = 0; nt < 4; nt++)
            attn_ws[base + nt * 16 + l15] = (_Float16)oacc[nt][reg];
    }
}

// K4a: per (b,r) softmax-over-L stats of lse
__global__ __launch_bounds__(256) void k_rw(const float* __restrict__ lse_ws,
                                            float* __restrict__ rwmax,
                                            float* __restrict__ rwsum) {
    __shared__ float  red[256];
    __shared__ double redd[256];
    int br = blockIdx.x;
    const float* lp = lse_ws + (size_t)br * L_;
    int t = threadIdx.x;
    float m = -1e30f;
    for (int k = t; k < L_; k += 256) m = fmaxf(m, lp[k]);
    red[t] = m; __syncthreads();
    for (int s2 = 128; s2 > 0; s2 >>= 1) {
        if (t < s2) red[t] = fmaxf(red[t], red[t + s2]);
        __syncthreads();
    }
    float mm = red[0];
    double s = 0.0;
    for (int k = t; k < L_; k += 256) s += (double)expf(lp[k] - mm);
    redd[t] = s; __syncthreads();
    for (int s2 = 128; s2 > 0; s2 >>= 1) {
        if (t < s2) redd[t] += redd[t + s2];
        __syncthreads();
    }
    if (t == 0) { rwmax[br] = mm; rwsum[br] = (float)redd[0]; }
}

// K4b: combine. XCD-pinned b; attn [B][L][R][64] -> 512 B contiguous per row.
__global__ __launch_bounds__(256) void k_out(const _Float16* __restrict__ attn_ws,
                                             const float* __restrict__ lse_ws,
                                             const float* __restrict__ rwmax,
                                             const float* __restrict__ rwsum,
                                             float* __restrict__ out) {
    int xcd = blockIdx.x & 7, slot = blockIdx.x >> 3;   // 256 slots
    int b = xcd * 2 + (slot >> 7);
    int inner = slot & 127;                              // 32 rows per block
    int tid = threadIdx.x;
    int l = inner * 32 + (tid >> 3), g = tid & 7;
    size_t row = (size_t)b * L_ + l;
    float o[8];
    #pragma unroll
    for (int k = 0; k < 8; k++) o[k] = 0.f;
    #pragma unroll
    for (int r = 0; r < 4; r++) {
        int br = b * 4 + r;
        float wgt = __expf(lse_ws[(size_t)br * L_ + l] - rwmax[br])
                  * __builtin_amdgcn_rcpf(rwsum[br]);
        f16x8 av = *(const f16x8*)&attn_ws[(row * 4 + r) * 64 + g * 8];
        #pragma unroll
        for (int k = 0; k < 8; k++) o[k] += (float)av[k] * wgt;
    }
    float4* op = (float4*)(out + row * 64 + g * 8);
    op[0] = make_float4(o[0], o[1], o[2], o[3]);
    op[1] = make_float4(o[4], o[5], o[6], o[7]);
}

extern "C" void kernel_launch(void* const* d_in, const int* in_sizes, int n_in,
                              void* d_out, int out_size, void* d_ws, size_t ws_size,
                              hipStream_t stream) {
    const float* query = (const float*)d_in[0];
    const float* value = (const float*)d_in[1];
    const float* rm    = (const float*)d_in[2];
    char* ws = (char*)d_ws;
    double*    rmn    = (double*)ws;
    int*       h_ws   = (int*)(ws + ((size_t)1 << 20));
    int*       hi_ws  = (int*)(ws + ((size_t)2 << 20));
    int*       oi_ws  = (int*)(ws + ((size_t)3 << 20));
    float*     lse_ws = (float*)(ws + ((size_t)4 << 20));
    float*     rwmax  = (float*)(ws + ((size_t)5 << 20));
    float*     rwsum  = (float*)(ws + ((size_t)5 << 20) + 256);
    int*       fix_cnt= (int*)(ws + ((size_t)5 << 20) + 512);
    int*       fix_list=(int*)(ws + ((size_t)5 << 20) + 1024);
    _Float16*  attn_ws= (_Float16*)(ws + ((size_t)6 << 20));
    _Float16*  rhi_g  = (_Float16*)(ws + ((size_t)40 << 20));
    _Float16*  rlo_g  = (_Float16*)(ws + ((size_t)40 << 20) + ((size_t)1 << 19));
    int4*      meta_ws= (int4*)(ws + ((size_t)41 << 20));
    _Float16*  qhf    = (_Float16*)(ws + ((size_t)45 << 20));
    _Float16*  khf    = (_Float16*)(ws + ((size_t)53 << 20));
    _Float16*  vhf    = (_Float16*)(ws + ((size_t)61 << 20));
    float*     out    = (float*)d_out;

    hipLaunchKernelGGL(k_rmnorm, dim3(2048), dim3(64),  0, stream, rm, rmn, rhi_g, rlo_g, fix_cnt);
    hipLaunchKernelGGL(k_hash,   dim3(1024), dim3(256), 0, stream, query, value, rhi_g, rlo_g,
                       h_ws, fix_cnt, fix_list, qhf, khf, vhf);
    hipLaunchKernelGGL(k_fix,    dim3(64),   dim3(64),  0, stream, query, rmn,
                       fix_cnt, fix_list, h_ws);
    hipLaunchKernelGGL(k_sort,   dim3(64),   dim3(256), 0, stream, h_ws, hi_ws, oi_ws);
    hipLaunchKernelGGL(k_meta,   dim3(1024), dim3(256), 0, stream, h_ws, hi_ws, oi_ws, meta_ws);
    hipLaunchKernelGGL(k_attn,   dim3(4096), dim3(256), 0, stream,
                       qhf, khf, vhf, meta_ws, lse_ws, attn_ws);
    hipLaunchKernelGGL(k_rw,     dim3(64),   dim3(256), 0, stream, lse_ws, rwmax, rwsum);
    hipLaunchKernelGGL(k_out,    dim3(2048), dim3(256), 0, stream,
                       attn_ws, lse_ws, rwmax, rwsum, out);
}